// Round 3
// baseline (42.370 us; speedup 1.0000x reference)
//
#include <hip/hip_runtime.h>
#include <stdint.h>

// Soft decision-tree ensemble, collapsed to:
//   out[b,c] = sum_t ( A'[t,c] + sum_{k<4} d[b,t,k]*B'[t,k,c] ) / (4 + d[b,t,3] + 1e-8)
//   d[b,t,k] = sigmoid( X[b,:] . W[t,k,:] + bias[t,k] ),  only internal nodes 0..3 matter.
// GEMM: 65536x512 @ 512x256 (fp16 MFMA), memory-bound on X (134 MB fp32, read once).
// R3: depth-2 pipeline. X: global->reg(f32)->cvt->LDS(f16), staged for kt+2.
//     W: global_load_lds f16, 3-buffer ring, staged for kt+2. One barrier +
//     one counted vmcnt(4) per K-step; waits only target loads >=1 iter old.

#define KDIM 512
#define PPT 3607

typedef _Float16 f16x8 __attribute__((ext_vector_type(8)));
typedef float f32x4 __attribute__((ext_vector_type(4)));

// ws layout (bytes):
//   [0, 262144)       Wh   : _Float16 [256 cols][512 k]   (col = t*4 + node)
//   [262144, 263168)  biasN: float[256]
//   [263168, 265728)  AB   : float[64][10]

__global__ __launch_bounds__(128) void prep_kernel(const float* __restrict__ p,
                                                   const float* __restrict__ tw,
                                                   _Float16* __restrict__ Wh,
                                                   float* __restrict__ biasN,
                                                   float* __restrict__ AB) {
    const int c = blockIdx.x;          // 0..255
    const int t = c >> 2, i = c & 3;
    const float* wsrc = p + t * PPT + i * KDIM;
    for (int k = threadIdx.x; k < KDIM; k += 128)
        Wh[c * KDIM + k] = (_Float16)wsrc[k];
    if (threadIdx.x == 0)
        biasN[c] = p[t * PPT + 7 * KDIM + i];
    if (threadIdx.x == 64 && c < 64) {
        const int tt = c;
        const float* lg = p + tt * PPT + 7 * 513;   // leaf logits, 8 x 2
        const float w = tw[tt];
        float ld[8][2];
#pragma unroll
        for (int j = 0; j < 8; ++j) {
            float a = lg[2 * j], b = lg[2 * j + 1];
            float m = fmaxf(a, b);
            float e0 = expf(a - m), e1 = expf(b - m);
            float s = e0 + e1;
            ld[j][0] = e0 / s; ld[j][1] = e1 / s;
        }
        float* o = AB + tt * 10;
#pragma unroll
        for (int cc = 0; cc < 2; ++cc) {
            o[0 + cc] = w * (ld[0][cc] + ld[2][cc] + ld[4][cc] + ld[6][cc]);
            o[2 + cc] = w * (ld[1][cc] - ld[2][cc]);
            o[4 + cc] = w * (ld[3][cc] - ld[4][cc]);
            o[6 + cc] = w * (ld[5][cc] - ld[6][cc]);
            o[8 + cc] = w * (ld[7][cc]);
        }
    }
}

// LDS map (73216 B / block, 2 blocks/CU):
//   xbuf[2]: f16 [128 rows][32 k] at b*8192   (8 KiB each)
//            physical slot p (16B granule, 4/row) holds logical slot p ^ ((row>>1)&3)
//   wbuf[3]: f16 [256 cols][32 k] at 16384 + m*16384  (16 KiB each)
//            k-halves swizzled: k' = k ^ (((col>>1)&3)<<3)  (8-half granule)
//   epilogue overlay (loop-dead): d [64][260] f32 at 0 (66560 B)
//   AB coeffs at 66560 (2560 B);  partials [8][64][2] f32 at 69120 (4096 B)
#define XBUF_STRIDE 8192
#define W_BASE 16384
#define WBUF_STRIDE 16384
#define EPI_STRIDE 260
#define AB_OFF 66560
#define PART_OFF 69120
#define LDS_BYTES 73216

__device__ __forceinline__ void gll16(const void* g, void* l) {
    __builtin_amdgcn_global_load_lds((const __attribute__((address_space(1))) uint32_t*)g,
                                     (__attribute__((address_space(3))) uint32_t*)l, 16, 0, 0);
}

__device__ __forceinline__ f16x8 cvt8(float4 a, float4 b) {
    f16x8 h;
    h[0] = (_Float16)a.x; h[1] = (_Float16)a.y; h[2] = (_Float16)a.z; h[3] = (_Float16)a.w;
    h[4] = (_Float16)b.x; h[5] = (_Float16)b.y; h[6] = (_Float16)b.z; h[7] = (_Float16)b.w;
    return h;
}

__global__ __launch_bounds__(512, 4) void main_kernel(const float* __restrict__ X,
                                                      const _Float16* __restrict__ Wh,
                                                      const float* __restrict__ biasN,
                                                      const float* __restrict__ ABg,
                                                      float* __restrict__ out) {
    extern __shared__ char smem[];
    const int tid = threadIdx.x;
    const int lane = tid & 63;
    const int w = tid >> 6;          // wave 0..7
    const int wm = w >> 2;           // 0..1 : 64-row half
    const int wn = w & 3;            // 0..3 : 64-col quarter
    const int gr0 = blockIdx.x * 128;

    // preload folded leaf coefficients (region untouched by staging); completes
    // (compiler-inserted waits) before any staging issues -> clean vmcnt slate.
    {
        float* abl = (float*)(smem + AB_OFF);
        for (int i = tid; i < 640; i += 512) abl[i] = ABg[i];
    }
    asm volatile("s_waitcnt vmcnt(0)" ::: "memory");

    // ---- X staging (reg hop): thread owns row = tid>>2, logical k-slot = tid&3 ----
    const float* Xrow = X + (size_t)(gr0 + (tid >> 2)) * KDIM + (tid & 3) * 8;
    const int wOffX = ((tid >> 2) << 6) + ((((tid & 3) ^ ((tid >> 3) & 3))) << 4); // bytes in xbuf

    // ---- W staging (gll, pre-swizzled source) ----
    const _Float16* srcW[2];
    int dW[2];
#pragma unroll
    for (int i = 0; i < 2; ++i) {
        int colW = i * 128 + w * 16 + (lane >> 2);            // 0..255
        int kW = ((lane & 3) << 3) ^ (((colW >> 1) & 3) << 3);
        srcW[i] = Wh + (size_t)colW * KDIM + kW;
        dW[i] = (i * 512 + w * 64 + lane) * 16;               // bytes within wbuf
    }

    // fragment-read constants
    const int kb = (lane >> 4) << 3;              // logical k-slot * 8 halves
    const int kws = kb ^ (((lane >> 1) & 3) << 3);            // W: swizzled k (halves)
    const int bColBase = (wn * 64 + (lane & 15)) * 32;        // W: col * 32 halves
    const int aOff = ((lane & 15) << 6)
                   + (((lane >> 4) ^ (((lane & 15) >> 1) & 3)) << 4); // X: bytes in xbuf half

    f32x4 acc[4][4];
#pragma unroll
    for (int rt = 0; rt < 4; ++rt)
#pragma unroll
        for (int nt = 0; nt < 4; ++nt)
            acc[rt][nt] = (f32x4){0.f, 0.f, 0.f, 0.f};

    float4 xr[2][2];

    // ---- prologue: X0 (temps, written immediately), W0, X1, W1 ----
    {
        float4 x0a = *(const float4*)(Xrow + 0);
        float4 x0b = *(const float4*)(Xrow + 4);
        gll16(srcW[0] + 0 * 32, smem + W_BASE + 0 * WBUF_STRIDE + dW[0]);
        gll16(srcW[1] + 0 * 32, smem + W_BASE + 0 * WBUF_STRIDE + dW[1]);
        xr[1][0] = *(const float4*)(Xrow + 1 * 32);
        xr[1][1] = *(const float4*)(Xrow + 1 * 32 + 4);
        gll16(srcW[0] + 1 * 32, smem + W_BASE + 1 * WBUF_STRIDE + dW[0]);
        gll16(srcW[1] + 1 * 32, smem + W_BASE + 1 * WBUF_STRIDE + dW[1]);
        // compiler inserts precise vmcnt before use of x0a/x0b (leaves W0,X1,W1 in flight)
        *(f16x8*)(smem + 0 * XBUF_STRIDE + wOffX) = cvt8(x0a, x0b);
    }

#pragma unroll 16
    for (int kt = 0; kt < 16; ++kt) {
        // a: issue X(kt+2) into regs
        if (kt <= 13) {
            xr[kt & 1][0] = *(const float4*)(Xrow + (kt + 2) * 32);
            xr[kt & 1][1] = *(const float4*)(Xrow + (kt + 2) * 32 + 4);
        }
        // b: counted wait — certifies {W(kt), X(kt+1)} (issued 1-2 iters ago);
        //    never touches loads issued this iteration.
        if (kt <= 13)      asm volatile("s_waitcnt vmcnt(4)" ::: "memory");
        else if (kt == 14) asm volatile("s_waitcnt vmcnt(2)" ::: "memory");
        else               asm volatile("s_waitcnt vmcnt(0)" ::: "memory");
        // c: single barrier per step: all waves certified their W(kt)/X(kt) data,
        //    and all readers of the buffers about to be overwritten are done.
        __builtin_amdgcn_s_barrier();
        // d: issue W(kt+2) gll into ring slot (kt+2)%3
        if (kt <= 13) {
            char* wb = smem + W_BASE + ((kt + 2) % 3) * WBUF_STRIDE;
            gll16(srcW[0] + (kt + 2) * 32, wb + dW[0]);
            gll16(srcW[1] + (kt + 2) * 32, wb + dW[1]);
        }
        // e: convert + ds_write X(kt+1) (loaded at kt-1) into xbuf[(kt+1)&1]
        if (kt <= 14)
            *(f16x8*)(smem + ((kt + 1) & 1) * XBUF_STRIDE + wOffX) =
                cvt8(xr[(kt + 1) & 1][0], xr[(kt + 1) & 1][1]);
        // f: compute step kt from xbuf[kt&1], wbuf[kt%3]
        {
            const _Float16* Wl = (const _Float16*)(smem + W_BASE + (kt % 3) * WBUF_STRIDE);
            const char* Xl = smem + (kt & 1) * XBUF_STRIDE + wm * 4096;
            f16x8 bfr[4];
#pragma unroll
            for (int nt = 0; nt < 4; ++nt)
                bfr[nt] = *(const f16x8*)&Wl[bColBase + nt * 512 + kws];
#pragma unroll
            for (int rt = 0; rt < 4; ++rt) {
                f16x8 af = *(const f16x8*)(Xl + rt * 1024 + aOff);
#pragma unroll
                for (int nt = 0; nt < 4; ++nt)
                    acc[rt][nt] = __builtin_amdgcn_mfma_f32_16x16x32_f16(af, bfr[nt], acc[rt][nt], 0, 0, 0);
            }
        }
    }

    // ---- epilogue: 2 passes of 64 rows, transpose via LDS overlay ----
    __syncthreads();   // all compute reads done before overlaying staging region

    for (int p = 0; p < 2; ++p) {
        if (wm == p) {
            float bl[4];
#pragma unroll
            for (int nt = 0; nt < 4; ++nt) bl[nt] = biasN[wn * 64 + nt * 16 + (lane & 15)];
            float* ep = (float*)smem;
#pragma unroll
            for (int rt = 0; rt < 4; ++rt)
#pragma unroll
                for (int nt = 0; nt < 4; ++nt) {
                    const int col = wn * 64 + nt * 16 + (lane & 15);
#pragma unroll
                    for (int reg = 0; reg < 4; ++reg) {
                        const int rowl = rt * 16 + ((lane >> 4) << 2) + reg;
                        float z = acc[rt][nt][reg] + bl[nt];
                        ep[rowl * EPI_STRIDE + col] = __builtin_amdgcn_rcpf(1.f + __expf(-z));
                    }
                }
        }
        __syncthreads();
        {   // all 8 waves: wave w sums trees w*8..w*8+7 for all 64 rows (lane = row)
            const float* ep = (const float*)smem;
            const float* abl = (const float*)(smem + AB_OFF);
            float* pb = (float*)(smem + PART_OFF);
            const int r = lane;
            float s0 = 0.f, s1 = 0.f;
#pragma unroll
            for (int j = 0; j < 8; ++j) {
                const int t = w * 8 + j;
                float4 dv = *(const float4*)&ep[r * EPI_STRIDE + t * 4];
                const float* abt = &abl[t * 10];
                float inv = __builtin_amdgcn_rcpf(4.f + dv.w + 1e-8f);
                s0 += (abt[0] + dv.x * abt[2] + dv.y * abt[4] + dv.z * abt[6] + dv.w * abt[8]) * inv;
                s1 += (abt[1] + dv.x * abt[3] + dv.y * abt[5] + dv.z * abt[7] + dv.w * abt[9]) * inv;
            }
            pb[(w * 64 + r) * 2 + 0] = s0;
            pb[(w * 64 + r) * 2 + 1] = s1;
        }
        __syncthreads();
        if (tid < 128) {
            const float* pb = (const float*)(smem + PART_OFF);
            const int r = tid >> 1, c = tid & 1;
            float s = 0.f;
#pragma unroll
            for (int g = 0; g < 8; ++g) s += pb[(g * 64 + r) * 2 + c];
            out[(size_t)(gr0 + p * 64 + r) * 2 + c] = s;
        }
        if (p == 0) __syncthreads();
    }
}

extern "C" void kernel_launch(void* const* d_in, const int* in_sizes, int n_in,
                              void* d_out, int out_size, void* d_ws, size_t ws_size,
                              hipStream_t stream) {
    const float* x  = (const float*)d_in[0];
    const float* tp = (const float*)d_in[1];
    const float* tw = (const float*)d_in[2];
    float* out = (float*)d_out;

    _Float16* Wh = (_Float16*)d_ws;
    float* biasN = (float*)((char*)d_ws + 262144);
    float* AB    = (float*)((char*)d_ws + 263168);

    (void)hipFuncSetAttribute((const void*)reinterpret_cast<const void*>(&main_kernel),
                              hipFuncAttributeMaxDynamicSharedMemorySize, LDS_BYTES);

    prep_kernel<<<256, 128, 0, stream>>>(tp, tw, Wh, biasN, AB);
    main_kernel<<<512, 512, LDS_BYTES, stream>>>(x, Wh, biasN, AB, out);
}